// Round 5
// baseline (149.283 us; speedup 1.0000x reference)
//
#include <hip/hip_runtime.h>

#define IMH 512
#define IMW 512
#define NPIX (IMH * IMW)
#define RS 516                 // padded row stride (floats); 516*4 B, 16B-divisible
#define PR 514                 // padded rows (1-px zero border, top-left origin (1,1))
#define PLANE (PR * RS)        // floats per plane
#define NCH 30                 // planes: 0..2 = Z, 3+ij*3+s = w_pre(s,ij)
#define NBORD 2052             // border cells per plane: 2*514 + 2*512

// ---------------- Kernel 1: pointwise Bayes update + sensitivity -> planar ws
__global__ __launch_bounds__(256)
void k1_pointwise(const float* __restrict__ obs,
                  const float* __restrict__ P,     // P[o*3+s]
                  const float* __restrict__ u_k,
                  const float* __restrict__ w_k,   // pix*27 + s*9 + ij
                  float* __restrict__ ws) {
    const int gtid = blockIdx.x * 256 + threadIdx.x;   // 0..NPIX-1

    // zero the 1-px borders of all 30 planes (disjoint from interior writes)
    for (int i = gtid; i < NCH * NBORD; i += NPIX) {
        const int pl = i / NBORD, r = i - pl * NBORD;
        int rr, cc;
        if (r < 514)       { rr = 0;            cc = r; }
        else if (r < 1028) { rr = 513;          cc = r - 514; }
        else if (r < 1540) { rr = r - 1028 + 1; cc = 0; }
        else               { rr = r - 1540 + 1; cc = 513; }
        ws[(size_t)pl * PLANE + rr * RS + cc] = 0.0f;
    }

    const int h = gtid >> 9, w = gtid & 511;
    const float ov[3] = {obs[gtid*3+0], obs[gtid*3+1], obs[gtid*3+2]};
    const float us[3] = {u_k[gtid*3+0], u_k[gtid*3+1], u_k[gtid*3+2]};

    float b[3], Bu[3], bu = 0.0f;
#pragma unroll
    for (int s = 0; s < 3; ++s) {
        b[s] = P[s] * ov[0] + P[3+s] * ov[1] + P[6+s] * ov[2];
        Bu[s] = b[s] * us[s];
        bu += Bu[s];
    }
    const float inv_bu = 1.0f / bu;
    float Z[3];
#pragma unroll
    for (int s = 0; s < 3; ++s) Z[s] = Bu[s] * inv_bu;

    const int base = (h + 1) * RS + (w + 1);
    ws[0*PLANE + base] = Z[0];
    ws[1*PLANE + base] = Z[1];
    ws[2*PLANE + base] = Z[2];

    const float* wk = w_k + (size_t)gtid * 27;
    float wv[27];
#pragma unroll
    for (int c = 0; c < 27; ++c) wv[c] = wk[c];   // 27 independent loads (MLP)

#pragma unroll
    for (int ij = 0; ij < 9; ++ij) {
        const int i = ij / 3, j = ij % 3;
        float du[3], sdu = 0.0f;
#pragma unroll
        for (int s = 0; s < 3; ++s) {
            float d = b[s] * wv[s*9 + ij];
            if (s == j) d += ov[i] * us[s];
            du[s] = d;
            sdu += d;
        }
#pragma unroll
        for (int s = 0; s < 3; ++s)
            ws[(size_t)(3 + ij*3 + s) * PLANE + base] = (du[s] - sdu * Z[s]) * inv_bu;
    }
}

// ---------------- Kernel 2: 3x3 conv (10 groups) + softmax + softmax-JVP
__global__ __launch_bounds__(256)
void k2_conv(const float* __restrict__ ws,
             const float* __restrict__ conv_w,   // (S_out,S_in,3,3)
             const float* __restrict__ conv_b,
             float* __restrict__ out) {
    const int gtid = blockIdx.x * 256 + threadIdx.x;
    const int h = gtid >> 9, w = gtid & 511;

    float cw[81];                                 // uniform -> SGPRs
#pragma unroll
    for (int i = 0; i < 81; ++i) cw[i] = conv_w[i];
    const float cb0 = conv_b[0], cb1 = conv_b[1], cb2 = conv_b[2];

    const int base = h * RS + w;                  // top-left of 3x3 window (padded)

    float acc[30];
#pragma unroll
    for (int i = 0; i < 30; ++i) acc[i] = 0.0f;

#pragma unroll
    for (int c = 0; c < NCH; ++c) {
        const int g = c / 3, si = c - g * 3;
        const float* pl = ws + (size_t)c * PLANE + base;
#pragma unroll
        for (int ky = 0; ky < 3; ++ky) {
            const float v0 = pl[ky*RS + 0];
            const float v1 = pl[ky*RS + 1];
            const float v2 = pl[ky*RS + 2];
            const int t = si * 9 + ky * 3;
            acc[g*3+0] += cw[0*27 + t] * v0 + cw[0*27 + t + 1] * v1 + cw[0*27 + t + 2] * v2;
            acc[g*3+1] += cw[1*27 + t] * v0 + cw[1*27 + t + 1] * v1 + cw[1*27 + t + 2] * v2;
            acc[g*3+2] += cw[2*27 + t] * v0 + cw[2*27 + t + 1] * v1 + cw[2*27 + t + 2] * v2;
        }
    }

    // softmax on group 0
    const float y0 = acc[0] + cb0, y1 = acc[1] + cb1, y2 = acc[2] + cb2;
    const float m = fmaxf(y0, fmaxf(y1, y2));
    const float e0 = __expf(y0 - m), e1 = __expf(y1 - m), e2 = __expf(y2 - m);
    const float inv = 1.0f / (e0 + e1 + e2);
    const float p0 = e0 * inv, p1 = e1 * inv, p2 = e2 * inv;

    out[gtid*3 + 0] = p0; out[gtid*3 + 1] = p1; out[gtid*3 + 2] = p2;

    // softmax JVP per tangent group; store w_kp1_O
    float* outw = out + (size_t)NPIX * 3 + (size_t)gtid * 27;
#pragma unroll
    for (int g = 1; g < 10; ++g) {
        const float a0 = acc[g*3+0], a1 = acc[g*3+1], a2 = acc[g*3+2];
        const float dot = p0*a0 + p1*a1 + p2*a2;
        const int ij = g - 1;
        outw[0*9 + ij] = p0 * (a0 - dot);
        outw[1*9 + ij] = p1 * (a1 - dot);
        outw[2*9 + ij] = p2 * (a2 - dot);
    }
}

extern "C" void kernel_launch(void* const* d_in, const int* in_sizes, int n_in,
                              void* d_out, int out_size, void* d_ws, size_t ws_size,
                              hipStream_t stream) {
    const float* obs    = (const float*)d_in[0];
    const float* P      = (const float*)d_in[1];
    const float* u_k    = (const float*)d_in[2];
    const float* w_k    = (const float*)d_in[3];
    const float* conv_w = (const float*)d_in[4];
    const float* conv_b = (const float*)d_in[5];
    float* out = (float*)d_out;
    float* ws  = (float*)d_ws;    // needs 30*514*516*4 B = 31.8 MB

    const int nblk = NPIX / 256;  // 1024
    k1_pointwise<<<nblk, 256, 0, stream>>>(obs, P, u_k, w_k, ws);
    k2_conv<<<nblk, 256, 0, stream>>>(ws, conv_w, conv_b, out);
}